// Round 1
// baseline (60.345 us; speedup 1.0000x reference)
//
#include <hip/hip_runtime.h>
#include <math.h>

// Problem constants
#define NCH   128      // DIM
#define HH    128
#define WW    128
#define NB    8        // batch
#define KS    7
#define MSIZE (128*7*128)   // [u][b][c]

// Separable DFT intermediates: M[u,b,c] = sum_a K[a,b,c] * exp(-2pi i * u*(a-3)/128)
__device__ float g_MAr[MSIZE];
__device__ float g_MAi[MSIZE];
__device__ float g_MBr[MSIZE];
__device__ float g_MBi[MSIZE];

// Kernel 1: build M arrays (A gets 0.9*tanh(A*decay) applied first).
__global__ void kern_factor(const float* __restrict__ A, const float* __restrict__ B) {
    int idx = blockIdx.x * blockDim.x + threadIdx.x;
    if (idx >= MSIZE) return;
    int c  = idx & 127;
    int ub = idx >> 7;
    int b  = ub % 7;
    int u  = ub / 7;

    const float W0 = -6.283185307179586f / 128.0f;
    float mar = 0.f, mai = 0.f, mbr = 0.f, mbi = 0.f;
    float db = (float)(b - 3);
#pragma unroll
    for (int a = 0; a < 7; ++a) {
        float da   = (float)(a - 3);
        float dist = sqrtf(da * da + db * db);
        float dec  = expf(-0.1f * dist);          // exp(-0.3*dist/center), center=3
        float ka   = 0.9f * tanhf(A[c * 49 + a * 7 + b] * dec);
        float kb   = B[c * 49 + a * 7 + b];
        float th   = W0 * (float)(u * (a - 3));
        float s, cc;
        sincosf(th, &s, &cc);                     // exp(i*th) = cc + i*s
        mar = fmaf(ka, cc, mar);
        mai = fmaf(ka, s,  mai);
        mbr = fmaf(kb, cc, mbr);
        mbi = fmaf(kb, s,  mbi);
    }
    g_MAr[idx] = mar;
    g_MAi[idx] = mai;
    g_MBr[idx] = mbr;
    g_MBi[idx] = mbi;
}

// Kernel 2: per (u,v,c) finish the DFT (7-term b-sum), form
// S = (1+A)(1+A^2)(1+A^4)(1+A^8), C = S*Bf, then apply out = C * x (complex)
// for all 8 batches. 256 threads: 8 v-points per block, 32 lanes x float4 = 128 ch.
__global__ void kern_main(const float* __restrict__ x, float* __restrict__ out) {
    __shared__ float s_cs[128];
    __shared__ float s_sn[128];
    int t = threadIdx.x;
    if (t < 128) {
        float th = (6.283185307179586f / 128.0f) * (float)t;
        float s, c;
        sincosf(th, &s, &c);
        s_cs[t] = c;
        s_sn[t] = s;
    }
    __syncthreads();

    int bid = blockIdx.x;              // 0..2047
    int u   = bid >> 4;                // 0..127
    int v   = ((bid & 15) << 3) + (t >> 5);   // 0..127
    int c0  = (t & 31) << 2;           // 0,4,...,124

    float Afr[4] = {0, 0, 0, 0}, Afi[4] = {0, 0, 0, 0};
    float Bfr[4] = {0, 0, 0, 0}, Bfi[4] = {0, 0, 0, 0};

#pragma unroll
    for (int b = 0; b < 7; ++b) {
        int p = (v * (b - 3)) & 127;           // q mod 128 (two's complement &)
        float wr = s_cs[p];
        float wi = -s_sn[p];                   // exp(-2pi i p/128)
        int mbase = (u * 7 + b) * 128 + c0;
        float mar[4], mai[4], mbr[4], mbi[4];
        *(float4*)mar = *(const float4*)(g_MAr + mbase);
        *(float4*)mai = *(const float4*)(g_MAi + mbase);
        *(float4*)mbr = *(const float4*)(g_MBr + mbase);
        *(float4*)mbi = *(const float4*)(g_MBi + mbase);
#pragma unroll
        for (int j = 0; j < 4; ++j) {
            Afr[j] = fmaf(mar[j], wr, fmaf(-mai[j], wi, Afr[j]));
            Afi[j] = fmaf(mar[j], wi, fmaf( mai[j], wr, Afi[j]));
            Bfr[j] = fmaf(mbr[j], wr, fmaf(-mbi[j], wi, Bfr[j]));
            Bfi[j] = fmaf(mbr[j], wi, fmaf( mbi[j], wr, Bfi[j]));
        }
    }

    // Geometric series S = sum_{k=0}^{15} A^k = (1+A)(1+A^2)(1+A^4)(1+A^8); C = S*Bf
    float cr[4], ci[4];
#pragma unroll
    for (int j = 0; j < 4; ++j) {
        float ar = Afr[j], ai = Afi[j];
        float a2r = ar * ar - ai * ai,   a2i = 2.f * ar * ai;
        float a4r = a2r * a2r - a2i * a2i, a4i = 2.f * a2r * a2i;
        float a8r = a4r * a4r - a4i * a4i, a8i = 2.f * a4r * a4i;
        float s1r = 1.f + ar,  s1i = ai;
        float s2r = 1.f + a2r, s2i = a2i;
        float pr  = s1r * s2r - s1i * s2i;
        float pi  = s1r * s2i + s1i * s2r;
        float s3r = 1.f + a4r, s3i = a4i;
        float qr  = pr * s3r - pi * s3i;
        float qi  = pr * s3i + pi * s3r;
        float s4r = 1.f + a8r, s4i = a8i;
        float Sr  = qr * s4r - qi * s4i;
        float Si  = qr * s4i + qi * s4r;
        cr[j] = Sr * Bfr[j] - Si * Bfi[j];
        ci[j] = Sr * Bfi[j] + Si * Bfr[j];
    }

    // Apply to all batches: out = C * x (complex), channels split [0:128)=re, [128:256)=im
#pragma unroll
    for (int bt = 0; bt < NB; ++bt) {
        size_t base = (((size_t)bt * HH + u) * WW + v) * (2 * NCH) + c0;
        float xr[4], xi[4], orr[4], oii[4];
        *(float4*)xr = *(const float4*)(x + base);
        *(float4*)xi = *(const float4*)(x + base + NCH);
#pragma unroll
        for (int j = 0; j < 4; ++j) {
            orr[j] = cr[j] * xr[j] - ci[j] * xi[j];
            oii[j] = cr[j] * xi[j] + ci[j] * xr[j];
        }
        *(float4*)(out + base)       = *(const float4*)orr;
        *(float4*)(out + base + NCH) = *(const float4*)oii;
    }
}

extern "C" void kernel_launch(void* const* d_in, const int* in_sizes, int n_in,
                              void* d_out, int out_size, void* d_ws, size_t ws_size,
                              hipStream_t stream) {
    const float* x = (const float*)d_in[0];   // (8,128,128,256) f32
    const float* A = (const float*)d_in[1];   // (128,7,7) f32
    const float* B = (const float*)d_in[2];   // (128,7,7) f32
    float* out = (float*)d_out;

    kern_factor<<<(MSIZE + 255) / 256, 256, 0, stream>>>(A, B);
    kern_main<<<2048, 256, 0, stream>>>(x, out);
}